// Round 9
// baseline (414.774 us; speedup 1.0000x reference)
//
#include <hip/hip_runtime.h>
#include <cstdint>
#include <cstddef>

#define T_DATA 20000
#define E_NO 2000
#define I_NO 500
#define SUB_NO 16
#define HID 256
#define T_SYN 200
#define T_ENC 80
#define W_IN 159   // 2*T_ENC-1

typedef __attribute__((ext_vector_type(8))) __bf16 bf16x8;
typedef __attribute__((ext_vector_type(8))) short short8;
typedef __attribute__((ext_vector_type(4))) float floatx4;
typedef __attribute__((ext_vector_type(4))) unsigned int uint4v;
typedef __attribute__((ext_vector_type(2))) unsigned int uint2v;

__device__ __forceinline__ float bf2f(unsigned short u) {
    union { unsigned int i; float f; } v; v.i = ((unsigned int)u) << 16; return v.f;
}
__device__ __forceinline__ unsigned short f2bf(float f) {
    union { float f; unsigned int i; } v; v.f = f;
    unsigned int r = v.i + 0x7FFFu + ((v.i >> 16) & 1u);
    return (unsigned short)(r >> 16);
}
__device__ __forceinline__ float inload(const void* p, int i, int isbf) {
    return isbf ? bf2f(((const unsigned short*)p)[i]) : ((const float*)p)[i];
}

// async global->LDS copy, 16B per active lane (wave-uniform base + lane*16)
__device__ __forceinline__ void async_cp16(const void* g, void* l) {
    __builtin_amdgcn_global_load_lds(
        (const __attribute__((address_space(1))) void*)g,
        (__attribute__((address_space(3))) void*)l, 16, 0, 0);
}

// per-block dtype detection: scan first 1024 u32 words of S_e (4 KB, L2-hot).
__device__ __forceinline__ int detect_bf(const void* Se, int* sfl) {
    if (threadIdx.x == 0) *sfl = 0;
    __syncthreads();
    const unsigned int* w = (const unsigned int*)Se;
    int la = 0;
    #pragma unroll
    for (int i = 0; i < 4; i++)
        la |= (w[i * 256 + threadIdx.x] & 0xFFFFu) ? 1 : 0;
    if (la) atomicOr(sfl, 1);
    __syncthreads();
    return *sfl;
}

// ---------------- ws layout (bytes, all 16B aligned) ----------------
#define OFF_KERE   16u        // 16*200 f32
#define OFF_KERI   12816u
#define OFF_W1H    25616u     // 256*160 bf16
#define OFF_W1L    107536u
#define OFF_W2H    189456u    // 256*256 bf16
#define OFF_W2L    320528u
#define OFF_W3H    451600u
#define OFF_W3L    582672u
#define OFF_W4H    713744u    // 15*256 bf16
#define OFF_W4L    721424u
#define OFF_INE    729104u    // 20000*16 u8
#define OFF_INI    1049104u   // total 1369104 bytes

__device__ __forceinline__ void acc_slot(unsigned int b, unsigned int sh,
                                         unsigned long long& lo, unsigned long long& hi) {
    unsigned int up = sh >> 6;
    unsigned int s6 = sh & 63;
    lo += (unsigned long long)(b & (up ^ 1u)) << s6;
    hi += (unsigned long long)(b & up) << s6;
}

#define SPIKE_BLOCKS 1250
#define SETUP_BLOCKS 712

// ============ kernel 1 (fused): spikes + setup, role by blockIdx ============
// BF spike path: block's 16 Se rows (64000 B, contiguous) + 16 Si rows
// (16000 B) staged to LDS via global_load_lds (deep async queue, ZERO VGPR
// cost -> in-flight bytes no longer trade against occupancy; r8's register
// batching failed exactly on that trade). Table build overlaps the transfer.
__global__ void __launch_bounds__(256) k_front(
        const void* Se, const void* Si, const void* Ce, const void* Ci,
        const void* Ksyn, const void* tau_syn, const void* dly,
        const void* W1, const void* W2, const void* W3, const void* W4,
        float* ker_e, float* ker_i,
        unsigned short* W1h, unsigned short* W1l,
        unsigned short* W2h, unsigned short* W2l,
        unsigned short* W3h, unsigned short* W3l,
        unsigned short* W4h, unsigned short* W4l,
        unsigned char* in_e, unsigned char* in_i) {
    __shared__ int sfl;
    __shared__ __align__(16) unsigned char seb[64000];   // 16 rows x 4000 B (bf16)
    __shared__ __align__(16) unsigned char sib[16000];   // 16 rows x 1000 B
    __shared__ __align__(8) unsigned char she[2000];
    __shared__ __align__(8) unsigned char shi[500];
    int tid = threadIdx.x;

    if (blockIdx.x < SPIKE_BLOCKS) {
        int f = detect_bf(Se, &sfl);
        int lane = tid & 63, wave = tid >> 6;
        int tb = blockIdx.x * 16;

        if (f) {
            // ---- issue async staging FIRST (overlaps table build) ----
            const char* seG = (const char*)Se + (size_t)tb * 4000;
            const char* siG = (const char*)Si + (size_t)tb * 1000;
            for (int i = wave; i < 63; i += 4) {          // 64000 B = 62x1024 + 512
                int off = i * 1024 + lane * 16;
                if (i < 62)            async_cp16(seG + off, seb + off);
                else if (lane < 32)    async_cp16(seG + off, seb + off);
            }
            for (int i = wave; i < 16; i += 4) {          // 16000 B = 15x1024 + 640
                int off = i * 1024 + lane * 16;
                if (i < 15)            async_cp16(siG + off, sib + off);
                else if (lane < 40)    async_cp16(siG + off, sib + off);
            }
        }
        // ---- build synapse->subunit tables (reads C from L2) ----
        for (int e = tid; e < E_NO; e += 256) {
            int a = 0;
            for (int s = 0; s < 16; s++) if (inload(Ce, s * E_NO + e, f) > 0.5f) a = s;
            she[e] = (unsigned char)(a * 8);
        }
        for (int e = tid; e < I_NO; e += 256) {
            int a = 0;
            for (int s = 0; s < 16; s++) if (inload(Ci, s * I_NO + e, f) > 0.5f) a = s;
            shi[e] = (unsigned char)(a * 8);
        }
        __syncthreads();   // drains vmcnt (async LDS writes) + table writes

        if (f) {
            // ---- decode 4 rows/wave from LDS (branchless) ----
            #pragma unroll
            for (int rr = 0; rr < 4; rr++) {
                int r = wave * 4 + rr;
                unsigned long long e0 = 0, e1 = 0, i0 = 0, i1 = 0;
                #pragma unroll
                for (int it = 0; it < 4; it++) {
                    int c = it * 64 + lane;
                    int cc = c < 250 ? c : 0;
                    uint4v v = c < 250 ? *(const uint4v*)&seb[r * 4000 + c * 16]
                                       : (uint4v){0u, 0u, 0u, 0u};
                    unsigned long long q = *(const unsigned long long*)&she[cc * 8];
                    #pragma unroll
                    for (int w = 0; w < 4; w++) {
                        unsigned int x = v[w];
                        acc_slot((x >> 7) & 1u,  (unsigned int)(q >> (16 * w)) & 0xFFu, e0, e1);
                        acc_slot((x >> 23) & 1u, (unsigned int)(q >> (16 * w + 8)) & 0xFFu, e0, e1);
                    }
                }
                #pragma unroll
                for (int it = 0; it < 2; it++) {
                    int c = it * 64 + lane;
                    int cc = c < 125 ? c : 0;
                    uint2v v = c < 125 ? *(const uint2v*)&sib[r * 1000 + c * 8]
                                       : (uint2v){0u, 0u};
                    unsigned int q = *(const unsigned int*)&shi[cc * 4];
                    #pragma unroll
                    for (int w = 0; w < 2; w++) {
                        unsigned int x = v[w];
                        acc_slot((x >> 7) & 1u,  (q >> (16 * w)) & 0xFFu, i0, i1);
                        acc_slot((x >> 23) & 1u, (q >> (16 * w + 8)) & 0xFFu, i0, i1);
                    }
                }
                for (int off = 32; off; off >>= 1) {
                    e0 += __shfl_xor(e0, off);
                    e1 += __shfl_xor(e1, off);
                    i0 += __shfl_xor(i0, off);
                    i1 += __shfl_xor(i1, off);
                }
                int t = tb + r;
                if (lane < 16) {
                    unsigned long long a = (lane < 8) ? e0 : e1;
                    in_e[(size_t)t * 16 + lane] = (unsigned char)((a >> ((lane & 7) * 8)) & 0xFF);
                } else if (lane < 32) {
                    int s = lane - 16;
                    unsigned long long a = (s < 8) ? i0 : i1;
                    in_i[(size_t)t * 16 + s] = (unsigned char)((a >> ((s & 7) * 8)) & 0xFF);
                }
            }
        } else {
            // ---- f32 cold path: r7-style global register decode, 4 rows/wave ----
            uint4v z4 = {0u, 0u, 0u, 0u};
            uint2v z2 = {0u, 0u};
            #pragma unroll
            for (int rr = 0; rr < 4; rr++) {
                int t = tb + wave * 4 + rr;
                unsigned long long e0 = 0, e1 = 0, i0 = 0, i1 = 0;
                const uint4v* re = (const uint4v*)((const float*)Se + (size_t)t * E_NO);
                #pragma unroll
                for (int it = 0; it < 8; it++) {
                    int c = it * 64 + lane;
                    uint4v v = (c < 500) ? re[c] : z4;
                    unsigned int q = *(const unsigned int*)&she[(c < 500 ? c : 0) * 4];
                    #pragma unroll
                    for (int w = 0; w < 4; w++)
                        acc_slot((v[w] >> 23) & 1u, (q >> (8 * w)) & 0xFFu, e0, e1);
                }
                const uint2v* ri = (const uint2v*)((const float*)Si + (size_t)t * I_NO);
                #pragma unroll
                for (int it = 0; it < 4; it++) {
                    int c = it * 64 + lane;
                    uint2v v = (c < 250) ? ri[c] : z2;
                    unsigned int q = *(const unsigned short*)&shi[(c < 250 ? c : 0) * 2];
                    #pragma unroll
                    for (int w = 0; w < 2; w++)
                        acc_slot((v[w] >> 23) & 1u, (q >> (8 * w)) & 0xFFu, i0, i1);
                }
                for (int off = 32; off; off >>= 1) {
                    e0 += __shfl_xor(e0, off);
                    e1 += __shfl_xor(e1, off);
                    i0 += __shfl_xor(i0, off);
                    i1 += __shfl_xor(i1, off);
                }
                if (lane < 16) {
                    unsigned long long a = (lane < 8) ? e0 : e1;
                    in_e[(size_t)t * 16 + lane] = (unsigned char)((a >> ((lane & 7) * 8)) & 0xFF);
                } else if (lane < 32) {
                    int s = lane - 16;
                    unsigned long long a = (s < 8) ? i0 : i1;
                    in_i[(size_t)t * 16 + s] = (unsigned char)((a >> ((s & 7) * 8)) & 0xFF);
                }
            }
        }
    } else {
        int f = detect_bf(Se, &sfl);
        int id = (blockIdx.x - SPIKE_BLOCKS) * 256 + tid;
        if (id < 6400) {
            int c = id < 3200 ? 0 : 1;
            int q = id - c * 3200;
            int s = q / 200, j = q - s * 200;
            float d = expf(inload(dly, s * 2 + c, f));
            float tt = fmaxf((float)j - d, 0.0f);
            float acc = 0.f;
            #pragma unroll
            for (int b = 0; b < 3; b++) {
                float tau = expf(inload(tau_syn, b * 3 + c, f));
                float x = tt / tau;
                acc += x * expf(-x) * inload(Ksyn, (s * 3 + b) * 3 + c, f);
            }
            (c == 0 ? ker_e : ker_i)[s * 200 + j] = acc;
        } else if (id < 47360) {          // W1 pad 159->160 + hi/lo
            int q = id - 6400;
            int n = q / 160, k = q - n * 160;
            float v = (k < W_IN) ? inload(W1, n * W_IN + k, f) : 0.f;
            unsigned short hi = f2bf(v);
            W1h[q] = hi;
            W1l[q] = f2bf(v - bf2f(hi));
        } else if (id < 112896) {         // W2
            int q = id - 47360;
            float v = inload(W2, q, f);
            unsigned short hi = f2bf(v);
            W2h[q] = hi;
            W2l[q] = f2bf(v - bf2f(hi));
        } else if (id < 178432) {         // W3
            int q = id - 112896;
            float v = inload(W3, q, f);
            unsigned short hi = f2bf(v);
            W3h[q] = hi;
            W3l[q] = f2bf(v - bf2f(hi));
        } else if (id < 182272) {         // W4
            int q = id - 178432;
            float v = inload(W4, q, f);
            unsigned short hi = f2bf(v);
            W4h[q] = hi;
            W4l[q] = f2bf(v - bf2f(hi));
        }
    }
}

// ============ kernel 2 (fused): conv tile (LDS) + sliding-window MLP ============
template<bool BF>
__device__ __forceinline__ void mlp_body(
    const void* V,
    const unsigned short* W1h, const unsigned short* W1l, const void* b1, const void* a1p,
    const unsigned short* W2h, const unsigned short* W2l, const void* b2, const void* a2p,
    const unsigned short* W3h, const unsigned short* W3l, const void* b3, const void* a3p,
    const unsigned short* W4h, const unsigned short* W4l, const void* b4,
    const void* encb, const float* sc, void* out,
    unsigned short* Ahi, unsigned short* Alo)
{
    int tid = threadIdx.x;
    int lane = tid & 63, wave = tid >> 6;
    int lm = lane & 15, quad = lane >> 4;
    int t0 = blockIdx.x * 64;

    auto ld = [&](const void* p, int i) -> float {
        return BF ? bf2f(((const unsigned short*)p)[i]) : ((const float*)p)[i];
    };

    for (int idx = tid; idx < 64 * 160; idx += 256) {
        int m = idx / 160, k = idx - m * 160;
        int tg = t0 + m + k - (T_ENC - 1);
        float v = 0.f;
        if (k < W_IN && tg >= 0 && tg < T_DATA) v = ld(V, tg);
        unsigned short hi = f2bf(v);
        int col = (((k >> 3) ^ (m & 31)) << 3) | (k & 7);
        Ahi[m * 256 + col] = hi;
        if (!BF) Alo[m * 256 + col] = f2bf(v - bf2f(hi));
    }
    __syncthreads();

    floatx4 acc[4][4];
    auto aoff = [&](int mt, int ks) {
        int arow = mt * 16 + lm;
        return arow * 256 + ((((ks << 2) | quad) ^ (arow & 31)) << 3);
    };

    auto epi = [&](const void* bias, float alpha) {
        __syncthreads();
        #pragma unroll
        for (int mt = 0; mt < 4; mt++) {
            #pragma unroll
            for (int nt = 0; nt < 4; nt++) {
                int cn = wave * 64 + nt * 16 + lm;
                float bb = ld(bias, cn);
                #pragma unroll
                for (int j = 0; j < 4; j++) {
                    int row = mt * 16 + quad * 4 + j;
                    float h = acc[mt][nt][j] + bb;
                    h = (h >= 0.f) ? h : alpha * h;
                    unsigned short hi = f2bf(h);
                    int col = (((cn >> 3) ^ (row & 31)) << 3) | (cn & 7);
                    Ahi[row * 256 + col] = hi;
                    if (!BF) Alo[row * 256 + col] = f2bf(h - bf2f(hi));
                }
            }
        }
        __syncthreads();
    };

    floatx4 z = {0.f, 0.f, 0.f, 0.f};
    // ---- layer 1: K=160 ----
    {
        #pragma unroll
        for (int mt = 0; mt < 4; mt++)
            #pragma unroll
            for (int nt = 0; nt < 4; nt++) acc[mt][nt] = z;
        if (BF) {
            bf16x8 Bh[5][4];
            #pragma unroll
            for (int ks = 0; ks < 5; ks++)
                #pragma unroll
                for (int nt = 0; nt < 4; nt++)
                    Bh[ks][nt] = *(const bf16x8*)(W1h + (size_t)(wave * 64 + nt * 16 + lm) * 160 + ks * 32 + quad * 8);
            #pragma unroll
            for (int ks = 0; ks < 5; ks++) {
                bf16x8 a[4];
                #pragma unroll
                for (int mt = 0; mt < 4; mt++) a[mt] = *(const bf16x8*)&Ahi[aoff(mt, ks)];
                #pragma unroll
                for (int nt = 0; nt < 4; nt++)
                    #pragma unroll
                    for (int mt = 0; mt < 4; mt++)
                        acc[mt][nt] = __builtin_amdgcn_mfma_f32_16x16x32_bf16(a[mt], Bh[ks][nt], acc[mt][nt], 0, 0, 0);
            }
        } else {
            for (int ks = 0; ks < 5; ks++) {
                bf16x8 ah[4], al[4];
                #pragma unroll
                for (int mt = 0; mt < 4; mt++) {
                    ah[mt] = *(const bf16x8*)&Ahi[aoff(mt, ks)];
                    al[mt] = *(const bf16x8*)&Alo[aoff(mt, ks)];
                }
                #pragma unroll
                for (int nt = 0; nt < 4; nt++) {
                    size_t bo = (size_t)(wave * 64 + nt * 16 + lm) * 160 + ks * 32 + quad * 8;
                    bf16x8 bh = *(const bf16x8*)(W1h + bo);
                    bf16x8 bl = *(const bf16x8*)(W1l + bo);
                    #pragma unroll
                    for (int mt = 0; mt < 4; mt++) {
                        acc[mt][nt] = __builtin_amdgcn_mfma_f32_16x16x32_bf16(ah[mt], bh, acc[mt][nt], 0, 0, 0);
                        acc[mt][nt] = __builtin_amdgcn_mfma_f32_16x16x32_bf16(al[mt], bh, acc[mt][nt], 0, 0, 0);
                        acc[mt][nt] = __builtin_amdgcn_mfma_f32_16x16x32_bf16(ah[mt], bl, acc[mt][nt], 0, 0, 0);
                    }
                }
            }
        }
        epi(b1, ld(a1p, 0));
    }
    // ---- layers 2,3: K=256 ----
    const unsigned short* Whs[2] = {W2h, W3h};
    const unsigned short* Wls[2] = {W2l, W3l};
    const void* bs[2] = {b2, b3};
    const void* as_[2] = {a2p, a3p};
    for (int l = 0; l < 2; l++) {
        #pragma unroll
        for (int mt = 0; mt < 4; mt++)
            #pragma unroll
            for (int nt = 0; nt < 4; nt++) acc[mt][nt] = z;
        const unsigned short* Wh = Whs[l];
        const unsigned short* Wl = Wls[l];
        if (BF) {
            bf16x8 Bh[8][4];
            #pragma unroll
            for (int ks = 0; ks < 8; ks++)
                #pragma unroll
                for (int nt = 0; nt < 4; nt++)
                    Bh[ks][nt] = *(const bf16x8*)(Wh + (size_t)(wave * 64 + nt * 16 + lm) * 256 + ks * 32 + quad * 8);
            #pragma unroll
            for (int ks = 0; ks < 8; ks++) {
                bf16x8 a[4];
                #pragma unroll
                for (int mt = 0; mt < 4; mt++) a[mt] = *(const bf16x8*)&Ahi[aoff(mt, ks)];
                #pragma unroll
                for (int nt = 0; nt < 4; nt++)
                    #pragma unroll
                    for (int mt = 0; mt < 4; mt++)
                        acc[mt][nt] = __builtin_amdgcn_mfma_f32_16x16x32_bf16(a[mt], Bh[ks][nt], acc[mt][nt], 0, 0, 0);
            }
        } else {
            for (int ks = 0; ks < 8; ks++) {
                bf16x8 ah[4], al[4];
                #pragma unroll
                for (int mt = 0; mt < 4; mt++) {
                    ah[mt] = *(const bf16x8*)&Ahi[aoff(mt, ks)];
                    al[mt] = *(const bf16x8*)&Alo[aoff(mt, ks)];
                }
                #pragma unroll
                for (int nt = 0; nt < 4; nt++) {
                    size_t bo = (size_t)(wave * 64 + nt * 16 + lm) * 256 + ks * 32 + quad * 8;
                    bf16x8 bh = *(const bf16x8*)(Wh + bo);
                    bf16x8 bl = *(const bf16x8*)(Wl + bo);
                    #pragma unroll
                    for (int mt = 0; mt < 4; mt++) {
                        acc[mt][nt] = __builtin_amdgcn_mfma_f32_16x16x32_bf16(ah[mt], bh, acc[mt][nt], 0, 0, 0);
                        acc[mt][nt] = __builtin_amdgcn_mfma_f32_16x16x32_bf16(al[mt], bh, acc[mt][nt], 0, 0, 0);
                        acc[mt][nt] = __builtin_amdgcn_mfma_f32_16x16x32_bf16(ah[mt], bl, acc[mt][nt], 0, 0, 0);
                    }
                }
            }
        }
        epi(bs[l], ld(as_[l], 0));
    }
    // ---- layer 4 + sigmoid; S_conv from LDS sc ----
    {
        int mt = wave;
        short8 z8 = {0, 0, 0, 0, 0, 0, 0, 0};
        bf16x8 bz = __builtin_bit_cast(bf16x8, z8);
        floatx4 a4 = z;
        #pragma unroll
        for (int ks = 0; ks < 8; ks++) {
            bf16x8 ah = *(const bf16x8*)&Ahi[aoff(mt, ks)];
            bf16x8 bh = bz;
            if (lm < 15)
                bh = *(const bf16x8*)(W4h + (size_t)lm * 256 + ks * 32 + quad * 8);
            a4 = __builtin_amdgcn_mfma_f32_16x16x32_bf16(ah, bh, a4, 0, 0, 0);
            if (!BF) {
                bf16x8 al = *(const bf16x8*)&Alo[aoff(mt, ks)];
                bf16x8 bl = bz;
                if (lm < 15)
                    bl = *(const bf16x8*)(W4l + (size_t)lm * 256 + ks * 32 + quad * 8);
                a4 = __builtin_amdgcn_mfma_f32_16x16x32_bf16(al, bh, a4, 0, 0, 0);
                a4 = __builtin_amdgcn_mfma_f32_16x16x32_bf16(ah, bl, a4, 0, 0, 0);
            }
        }
        if (lm < 15) {
            float bb = ld(b4, lm) + ld(encb, lm);
            #pragma unroll
            for (int j = 0; j < 4; j++) {
                int row = mt * 16 + quad * 4 + j;
                int t = t0 + row;
                if (t < T_DATA) {
                    float x = a4[j] + bb + sc[row * 16 + lm + 1];
                    x = fminf(fmaxf(x, -40.f), 40.f);
                    float sg = 1.f / (1.f + expf(-x));
                    if (BF) ((unsigned short*)out)[(size_t)t * 15 + lm] = f2bf(sg);
                    else    ((float*)out)[(size_t)t * 15 + lm] = sg;
                }
            }
        }
    }
}

__global__ void __launch_bounds__(256, 2) k_back(
    const void* Se, const void* V,
    const unsigned char* in_e, const unsigned char* in_i,
    const float* ker_e, const float* ker_i,
    const unsigned short* W1h, const unsigned short* W1l, const void* b1, const void* a1p,
    const unsigned short* W2h, const unsigned short* W2l, const void* b2, const void* a2p,
    const unsigned short* W3h, const unsigned short* W3l, const void* b3, const void* a3p,
    const unsigned short* W4h, const unsigned short* W4l, const void* b4,
    const void* encb, void* out) {
    __shared__ __align__(16) char smem[65536];   // union: conv arrays / Ahi+Alo
    __shared__ __align__(16) float sc[64 * 16];  // this block's S_conv tile
    __shared__ int sfl;
    int f = detect_bf(Se, &sfl);
    int tid = threadIdx.x;
    int t0 = blockIdx.x * 64;

    // ---------- phase A: conv tile ----------
    {
        float* se = (float*)smem;            // 263*17
        float* si = se + 263 * 17;
        float* ke = si + 263 * 17;           // 16*201
        float* ki = ke + 16 * 201;           // total 61496 B
        for (int idx = tid; idx < 263 * 4; idx += 256) {
            int r = idx >> 2, wi = idx & 3;
            int t = t0 - 199 + r;
            unsigned int ve = 0, vi = 0;
            if (t >= 0 && t < T_DATA) {
                ve = ((const unsigned int*)in_e)[t * 4 + wi];
                vi = ((const unsigned int*)in_i)[t * 4 + wi];
            }
            #pragma unroll
            for (int b = 0; b < 4; b++) {
                se[r * 17 + wi * 4 + b] = (float)((ve >> (8 * b)) & 0xFF);
                si[r * 17 + wi * 4 + b] = (float)((vi >> (8 * b)) & 0xFF);
            }
        }
        for (int idx = tid; idx < 3200; idx += 256) {
            int s = idx / 200, j = idx - s * 200;
            ke[s * 201 + j] = ker_e[idx];
            ki[s * 201 + j] = ker_i[idx];
        }
        __syncthreads();
        int s = tid & 15, g4 = (tid >> 4) * 4;
        float a0 = 0.f, a1 = 0.f, a2 = 0.f, a3 = 0.f;
        float w0 = se[(g4 + 199) * 17 + s], w1 = se[(g4 + 200) * 17 + s];
        float w2 = se[(g4 + 201) * 17 + s], w3 = se[(g4 + 202) * 17 + s];
        float x0 = si[(g4 + 199) * 17 + s], x1 = si[(g4 + 200) * 17 + s];
        float x2 = si[(g4 + 201) * 17 + s], x3 = si[(g4 + 202) * 17 + s];
        #pragma unroll 4
        for (int j = 0; j < 200; j++) {
            float kej = ke[s * 201 + j];
            float kij = ki[s * 201 + j];
            a0 += w0 * kej + x0 * kij;
            a1 += w1 * kej + x1 * kij;
            a2 += w2 * kej + x2 * kij;
            a3 += w3 * kej + x3 * kij;
            int lr = g4 + 198 - j; lr = lr < 0 ? 0 : lr;
            float nw = se[lr * 17 + s], nx = si[lr * 17 + s];
            w3 = w2; w2 = w1; w1 = w0; w0 = nw;
            x3 = x2; x2 = x1; x1 = x0; x0 = nx;
        }
        sc[(g4 + 0) * 16 + s] = a0;
        sc[(g4 + 1) * 16 + s] = a1;
        sc[(g4 + 2) * 16 + s] = a2;
        sc[(g4 + 3) * 16 + s] = a3;
        __syncthreads();   // conv reads done before MLP overwrites smem
    }

    // ---------- phase B: MLP ----------
    unsigned short* Ahi = (unsigned short*)smem;
    unsigned short* Alo = Ahi + 64 * 256;
    if (f)
        mlp_body<true>(V, W1h, W1l, b1, a1p, W2h, W2l, b2, a2p, W3h, W3l, b3, a3p,
                       W4h, W4l, b4, encb, sc, out, Ahi, Alo);
    else
        mlp_body<false>(V, W1h, W1l, b1, a1p, W2h, W2l, b2, a2p, W3h, W3l, b3, a3p,
                        W4h, W4l, b4, encb, sc, out, Ahi, Alo);
}

extern "C" void kernel_launch(void* const* d_in, const int* in_sizes, int n_in,
                              void* d_out, int out_size, void* d_ws, size_t ws_size,
                              hipStream_t stream) {
    const void* V    = d_in[0];
    const void* Se   = d_in[1];
    const void* Si   = d_in[2];
    const void* Ce   = d_in[3];
    const void* Ci   = d_in[4];
    const void* Ksyn = d_in[5];
    const void* tau  = d_in[6];
    const void* dly  = d_in[7];
    const void* encb = d_in[8];
    const void* W1   = d_in[9];
    const void* b1   = d_in[10];
    const void* a1   = d_in[11];
    const void* W2   = d_in[12];
    const void* b2   = d_in[13];
    const void* a2   = d_in[14];
    const void* W3   = d_in[15];
    const void* b3   = d_in[16];
    const void* a3   = d_in[17];
    const void* W4   = d_in[18];
    const void* b4   = d_in[19];

    char* w = (char*)d_ws;
    float* ker_e = (float*)(w + OFF_KERE);
    float* ker_i = (float*)(w + OFF_KERI);
    unsigned short* W1h = (unsigned short*)(w + OFF_W1H);
    unsigned short* W1l = (unsigned short*)(w + OFF_W1L);
    unsigned short* W2h = (unsigned short*)(w + OFF_W2H);
    unsigned short* W2l = (unsigned short*)(w + OFF_W2L);
    unsigned short* W3h = (unsigned short*)(w + OFF_W3H);
    unsigned short* W3l = (unsigned short*)(w + OFF_W3L);
    unsigned short* W4h = (unsigned short*)(w + OFF_W4H);
    unsigned short* W4l = (unsigned short*)(w + OFF_W4L);
    unsigned char* in_e = (unsigned char*)(w + OFF_INE);
    unsigned char* in_i = (unsigned char*)(w + OFF_INI);

    k_front<<<SPIKE_BLOCKS + SETUP_BLOCKS, 256, 0, stream>>>(
        Se, Si, Ce, Ci, Ksyn, tau, dly, W1, W2, W3, W4,
        ker_e, ker_i, W1h, W1l, W2h, W2l, W3h, W3l, W4h, W4l, in_e, in_i);
    k_back<<<313, 256, 0, stream>>>(
        Se, V, in_e, in_i, ker_e, ker_i,
        W1h, W1l, b1, a1, W2h, W2l, b2, a2, W3h, W3l, b3, a3,
        W4h, W4l, b4, encb, d_out);
}

// Round 10
// 377.852 us; speedup vs baseline: 1.0977x; 1.0977x over previous
//
#include <hip/hip_runtime.h>
#include <cstdint>
#include <cstddef>

#define T_DATA 20000
#define E_NO 2000
#define I_NO 500
#define SUB_NO 16
#define HID 256
#define T_SYN 200
#define T_ENC 80
#define W_IN 159   // 2*T_ENC-1

typedef __attribute__((ext_vector_type(8))) __bf16 bf16x8;
typedef __attribute__((ext_vector_type(8))) short short8;
typedef __attribute__((ext_vector_type(4))) float floatx4;
typedef __attribute__((ext_vector_type(4))) unsigned int uint4v;
typedef __attribute__((ext_vector_type(2))) unsigned int uint2v;

__device__ __forceinline__ float bf2f(unsigned short u) {
    union { unsigned int i; float f; } v; v.i = ((unsigned int)u) << 16; return v.f;
}
__device__ __forceinline__ unsigned short f2bf(float f) {
    union { float f; unsigned int i; } v; v.f = f;
    unsigned int r = v.i + 0x7FFFu + ((v.i >> 16) & 1u);
    return (unsigned short)(r >> 16);
}
__device__ __forceinline__ float inload(const void* p, int i, int isbf) {
    return isbf ? bf2f(((const unsigned short*)p)[i]) : ((const float*)p)[i];
}

// per-block dtype detection: scan first 1024 u32 words of S_e (4 KB, L2-hot).
__device__ __forceinline__ int detect_bf(const void* Se, int* sfl) {
    if (threadIdx.x == 0) *sfl = 0;
    __syncthreads();
    const unsigned int* w = (const unsigned int*)Se;
    int la = 0;
    #pragma unroll
    for (int i = 0; i < 4; i++)
        la |= (w[i * 256 + threadIdx.x] & 0xFFFFu) ? 1 : 0;
    if (la) atomicOr(sfl, 1);
    __syncthreads();
    return *sfl;
}

// ---------------- ws layout (bytes, all 16B aligned) ----------------
#define OFF_KERE   16u        // 16*200 f32
#define OFF_KERI   12816u
#define OFF_W1H    25616u     // 256*160 bf16
#define OFF_W1L    107536u
#define OFF_W2H    189456u    // 256*256 bf16
#define OFF_W2L    320528u
#define OFF_W3H    451600u
#define OFF_W3L    582672u
#define OFF_W4H    713744u    // 15*256 bf16
#define OFF_W4L    721424u
#define OFF_INE    729104u    // 20000*16 u8
#define OFF_INI    1049104u   // total 1369104 bytes

#define SPIKE_BLOCKS 1250
#define SETUP_BLOCKS 712

// f32x8 (as 2 uint4) -> bf16x8 by taking high halves (exact for 0.0/1.0)
__device__ __forceinline__ bf16x8 hi_pack(uint4v u0, uint4v u1) {
    uint4v r;
    r[0] = (u0[0] >> 16) | (u0[1] & 0xFFFF0000u);
    r[1] = (u0[2] >> 16) | (u0[3] & 0xFFFF0000u);
    r[2] = (u1[0] >> 16) | (u1[1] & 0xFFFF0000u);
    r[3] = (u1[2] >> 16) | (u1[3] & 0xFFFF0000u);
    return __builtin_bit_cast(bf16x8, r);
}
// full 8-element frag at element index (in-bounds guaranteed by caller)
template<bool BF>
__device__ __forceinline__ bf16x8 ldfrag(const void* p, size_t idx) {
    if (BF) return *(const bf16x8*)((const unsigned short*)p + idx);
    const float* f = (const float*)p + idx;
    return hi_pack(*(const uint4v*)f, *(const uint4v*)(f + 4));
}
// 4 valid elements (low half), rest zero
template<bool BF>
__device__ __forceinline__ bf16x8 ldfrag4(const void* p, size_t idx) {
    uint4v r = {0u, 0u, 0u, 0u};
    if (BF) {
        uint2v u = *(const uint2v*)((const unsigned short*)p + idx);
        r[0] = u[0]; r[1] = u[1];
    } else {
        uint4v u = *(const uint4v*)((const float*)p + idx);
        r[0] = (u[0] >> 16) | (u[1] & 0xFFFF0000u);
        r[1] = (u[2] >> 16) | (u[3] & 0xFFFF0000u);
    }
    return __builtin_bit_cast(bf16x8, r);
}

// ============ spike counting AS MFMA GEMM: in = S @ C^T ============
// D[sub][t] = sum_e C[sub][e] * S[t][e]. A-frag = C (lane&15 = sub, L2-hot),
// B-frag = S rows (lane&15 = t, 16B contiguous, streamed at HBM BW).
// Block = 16 timesteps; K split across the 4 waves (E kgs 16/wave, I kgs
// 4/wave), LDS reduction. No decode ALU, no tables, no staging.
template<bool BF>
__device__ __forceinline__ void spike_gemm(const void* Se, const void* Si,
        const void* Ce, const void* Ci,
        unsigned char* in_e, unsigned char* in_i, float* red) {
    int tid = threadIdx.x;
    int lane = tid & 63, wave = tid >> 6;
    int lm = lane & 15, quad = lane >> 4;
    int t0 = blockIdx.x * 16;            // 1250*16 == 20000 exactly, no tail
    size_t teb = (size_t)(t0 + lm) * E_NO;
    size_t tib = (size_t)(t0 + lm) * I_NO;
    floatx4 ae = {0.f, 0.f, 0.f, 0.f}, ai = {0.f, 0.f, 0.f, 0.f};
    short8 zs = {0, 0, 0, 0, 0, 0, 0, 0};
    bf16x8 bz = __builtin_bit_cast(bf16x8, zs);

    // E: 63 k-groups of 32 (2000 = 62*32 + 16; kg62 valid only for quad<2)
    #pragma unroll
    for (int q = 0; q < 16; q++) {
        int kg = wave * 16 + q;
        int k0 = kg * 32 + quad * 8;
        bf16x8 a = bz, b = bz;
        if (kg < 63 && (kg < 62 || quad < 2)) {
            a = ldfrag<BF>(Ce, (size_t)lm * E_NO + k0);
            b = ldfrag<BF>(Se, teb + k0);
        }
        ae = __builtin_amdgcn_mfma_f32_16x16x32_bf16(a, b, ae, 0, 0, 0);
    }
    // I: 16 k-groups (500 = 15*32 + 20; kg15: quad0/1 full, quad2 low-4, quad3 zero)
    #pragma unroll
    for (int q = 0; q < 4; q++) {
        int kg = wave * 4 + q;
        int k0 = kg * 32 + quad * 8;
        bf16x8 a = bz, b = bz;
        if (kg < 15 || quad < 2) {
            a = ldfrag<BF>(Ci, (size_t)lm * I_NO + k0);
            b = ldfrag<BF>(Si, tib + k0);
        } else if (quad == 2) {
            a = ldfrag4<BF>(Ci, (size_t)lm * I_NO + k0);
            b = ldfrag4<BF>(Si, tib + k0);
        }
        ai = __builtin_amdgcn_mfma_f32_16x16x32_bf16(a, b, ai, 0, 0, 0);
    }
    // cross-wave K-reduction via LDS. D layout: col=lane&15=t, row=quad*4+j=sub
    float* re = red;            // [4][16sub][16t]
    float* ri = red + 1024;
    #pragma unroll
    for (int j = 0; j < 4; j++) {
        re[wave * 256 + (quad * 4 + j) * 16 + lm] = ae[j];
        ri[wave * 256 + (quad * 4 + j) * 16 + lm] = ai[j];
    }
    __syncthreads();
    if (tid < 64) {
        int t = tid >> 2, qd = tid & 3;
        unsigned pe = 0, pi = 0;
        #pragma unroll
        for (int j = 0; j < 4; j++) {
            float se_ = 0.f, si_ = 0.f;
            #pragma unroll
            for (int w = 0; w < 4; w++) {
                se_ += re[w * 256 + (qd * 4 + j) * 16 + t];
                si_ += ri[w * 256 + (qd * 4 + j) * 16 + t];
            }
            pe |= ((unsigned)(se_ + 0.5f) & 0xFFu) << (8 * j);
            pi |= ((unsigned)(si_ + 0.5f) & 0xFFu) << (8 * j);
        }
        ((unsigned*)in_e)[(t0 + t) * 4 + qd] = pe;
        ((unsigned*)in_i)[(t0 + t) * 4 + qd] = pi;
    }
}

// ============ kernel 1 (fused): spike-GEMM + setup, role by blockIdx ============
__global__ void __launch_bounds__(256) k_front(
        const void* Se, const void* Si, const void* Ce, const void* Ci,
        const void* Ksyn, const void* tau_syn, const void* dly,
        const void* W1, const void* W2, const void* W3, const void* W4,
        float* ker_e, float* ker_i,
        unsigned short* W1h, unsigned short* W1l,
        unsigned short* W2h, unsigned short* W2l,
        unsigned short* W3h, unsigned short* W3l,
        unsigned short* W4h, unsigned short* W4l,
        unsigned char* in_e, unsigned char* in_i) {
    __shared__ int sfl;
    __shared__ __align__(16) float red[2048];   // 8 KB reduction buffer
    int f = detect_bf(Se, &sfl);
    int tid = threadIdx.x;

    if (blockIdx.x < SPIKE_BLOCKS) {
        if (f) spike_gemm<true>(Se, Si, Ce, Ci, in_e, in_i, red);
        else   spike_gemm<false>(Se, Si, Ce, Ci, in_e, in_i, red);
    } else {
        int id = (blockIdx.x - SPIKE_BLOCKS) * 256 + tid;
        if (id < 6400) {
            int c = id < 3200 ? 0 : 1;
            int q = id - c * 3200;
            int s = q / 200, j = q - s * 200;
            float d = expf(inload(dly, s * 2 + c, f));
            float tt = fmaxf((float)j - d, 0.0f);
            float acc = 0.f;
            #pragma unroll
            for (int b = 0; b < 3; b++) {
                float tau = expf(inload(tau_syn, b * 3 + c, f));
                float x = tt / tau;
                acc += x * expf(-x) * inload(Ksyn, (s * 3 + b) * 3 + c, f);
            }
            (c == 0 ? ker_e : ker_i)[s * 200 + j] = acc;
        } else if (id < 47360) {          // W1 pad 159->160 + hi/lo
            int q = id - 6400;
            int n = q / 160, k = q - n * 160;
            float v = (k < W_IN) ? inload(W1, n * W_IN + k, f) : 0.f;
            unsigned short hi = f2bf(v);
            W1h[q] = hi;
            W1l[q] = f2bf(v - bf2f(hi));
        } else if (id < 112896) {         // W2
            int q = id - 47360;
            float v = inload(W2, q, f);
            unsigned short hi = f2bf(v);
            W2h[q] = hi;
            W2l[q] = f2bf(v - bf2f(hi));
        } else if (id < 178432) {         // W3
            int q = id - 112896;
            float v = inload(W3, q, f);
            unsigned short hi = f2bf(v);
            W3h[q] = hi;
            W3l[q] = f2bf(v - bf2f(hi));
        } else if (id < 182272) {         // W4
            int q = id - 178432;
            float v = inload(W4, q, f);
            unsigned short hi = f2bf(v);
            W4h[q] = hi;
            W4l[q] = f2bf(v - bf2f(hi));
        }
    }
}

// ============ kernel 2 (fused): conv tile (LDS) + sliding-window MLP ============
template<bool BF>
__device__ __forceinline__ void mlp_body(
    const void* V,
    const unsigned short* W1h, const unsigned short* W1l, const void* b1, const void* a1p,
    const unsigned short* W2h, const unsigned short* W2l, const void* b2, const void* a2p,
    const unsigned short* W3h, const unsigned short* W3l, const void* b3, const void* a3p,
    const unsigned short* W4h, const unsigned short* W4l, const void* b4,
    const void* encb, const float* sc, void* out,
    unsigned short* Ahi, unsigned short* Alo)
{
    int tid = threadIdx.x;
    int lane = tid & 63, wave = tid >> 6;
    int lm = lane & 15, quad = lane >> 4;
    int t0 = blockIdx.x * 64;

    auto ld = [&](const void* p, int i) -> float {
        return BF ? bf2f(((const unsigned short*)p)[i]) : ((const float*)p)[i];
    };

    for (int idx = tid; idx < 64 * 160; idx += 256) {
        int m = idx / 160, k = idx - m * 160;
        int tg = t0 + m + k - (T_ENC - 1);
        float v = 0.f;
        if (k < W_IN && tg >= 0 && tg < T_DATA) v = ld(V, tg);
        unsigned short hi = f2bf(v);
        int col = (((k >> 3) ^ (m & 31)) << 3) | (k & 7);
        Ahi[m * 256 + col] = hi;
        if (!BF) Alo[m * 256 + col] = f2bf(v - bf2f(hi));
    }
    __syncthreads();

    floatx4 acc[4][4];
    auto aoff = [&](int mt, int ks) {
        int arow = mt * 16 + lm;
        return arow * 256 + ((((ks << 2) | quad) ^ (arow & 31)) << 3);
    };

    auto epi = [&](const void* bias, float alpha) {
        __syncthreads();
        #pragma unroll
        for (int mt = 0; mt < 4; mt++) {
            #pragma unroll
            for (int nt = 0; nt < 4; nt++) {
                int cn = wave * 64 + nt * 16 + lm;
                float bb = ld(bias, cn);
                #pragma unroll
                for (int j = 0; j < 4; j++) {
                    int row = mt * 16 + quad * 4 + j;
                    float h = acc[mt][nt][j] + bb;
                    h = (h >= 0.f) ? h : alpha * h;
                    unsigned short hi = f2bf(h);
                    int col = (((cn >> 3) ^ (row & 31)) << 3) | (cn & 7);
                    Ahi[row * 256 + col] = hi;
                    if (!BF) Alo[row * 256 + col] = f2bf(h - bf2f(hi));
                }
            }
        }
        __syncthreads();
    };

    floatx4 z = {0.f, 0.f, 0.f, 0.f};
    // ---- layer 1: K=160 ----
    {
        #pragma unroll
        for (int mt = 0; mt < 4; mt++)
            #pragma unroll
            for (int nt = 0; nt < 4; nt++) acc[mt][nt] = z;
        if (BF) {
            bf16x8 Bh[5][4];
            #pragma unroll
            for (int ks = 0; ks < 5; ks++)
                #pragma unroll
                for (int nt = 0; nt < 4; nt++)
                    Bh[ks][nt] = *(const bf16x8*)(W1h + (size_t)(wave * 64 + nt * 16 + lm) * 160 + ks * 32 + quad * 8);
            #pragma unroll
            for (int ks = 0; ks < 5; ks++) {
                bf16x8 a[4];
                #pragma unroll
                for (int mt = 0; mt < 4; mt++) a[mt] = *(const bf16x8*)&Ahi[aoff(mt, ks)];
                #pragma unroll
                for (int nt = 0; nt < 4; nt++)
                    #pragma unroll
                    for (int mt = 0; mt < 4; mt++)
                        acc[mt][nt] = __builtin_amdgcn_mfma_f32_16x16x32_bf16(a[mt], Bh[ks][nt], acc[mt][nt], 0, 0, 0);
            }
        } else {
            for (int ks = 0; ks < 5; ks++) {
                bf16x8 ah[4], al[4];
                #pragma unroll
                for (int mt = 0; mt < 4; mt++) {
                    ah[mt] = *(const bf16x8*)&Ahi[aoff(mt, ks)];
                    al[mt] = *(const bf16x8*)&Alo[aoff(mt, ks)];
                }
                #pragma unroll
                for (int nt = 0; nt < 4; nt++) {
                    size_t bo = (size_t)(wave * 64 + nt * 16 + lm) * 160 + ks * 32 + quad * 8;
                    bf16x8 bh = *(const bf16x8*)(W1h + bo);
                    bf16x8 bl = *(const bf16x8*)(W1l + bo);
                    #pragma unroll
                    for (int mt = 0; mt < 4; mt++) {
                        acc[mt][nt] = __builtin_amdgcn_mfma_f32_16x16x32_bf16(ah[mt], bh, acc[mt][nt], 0, 0, 0);
                        acc[mt][nt] = __builtin_amdgcn_mfma_f32_16x16x32_bf16(al[mt], bh, acc[mt][nt], 0, 0, 0);
                        acc[mt][nt] = __builtin_amdgcn_mfma_f32_16x16x32_bf16(ah[mt], bl, acc[mt][nt], 0, 0, 0);
                    }
                }
            }
        }
        epi(b1, ld(a1p, 0));
    }
    // ---- layers 2,3: K=256 ----
    const unsigned short* Whs[2] = {W2h, W3h};
    const unsigned short* Wls[2] = {W2l, W3l};
    const void* bs[2] = {b2, b3};
    const void* as_[2] = {a2p, a3p};
    for (int l = 0; l < 2; l++) {
        #pragma unroll
        for (int mt = 0; mt < 4; mt++)
            #pragma unroll
            for (int nt = 0; nt < 4; nt++) acc[mt][nt] = z;
        const unsigned short* Wh = Whs[l];
        const unsigned short* Wl = Wls[l];
        if (BF) {
            bf16x8 Bh[8][4];
            #pragma unroll
            for (int ks = 0; ks < 8; ks++)
                #pragma unroll
                for (int nt = 0; nt < 4; nt++)
                    Bh[ks][nt] = *(const bf16x8*)(Wh + (size_t)(wave * 64 + nt * 16 + lm) * 256 + ks * 32 + quad * 8);
            #pragma unroll
            for (int ks = 0; ks < 8; ks++) {
                bf16x8 a[4];
                #pragma unroll
                for (int mt = 0; mt < 4; mt++) a[mt] = *(const bf16x8*)&Ahi[aoff(mt, ks)];
                #pragma unroll
                for (int nt = 0; nt < 4; nt++)
                    #pragma unroll
                    for (int mt = 0; mt < 4; mt++)
                        acc[mt][nt] = __builtin_amdgcn_mfma_f32_16x16x32_bf16(a[mt], Bh[ks][nt], acc[mt][nt], 0, 0, 0);
            }
        } else {
            for (int ks = 0; ks < 8; ks++) {
                bf16x8 ah[4], al[4];
                #pragma unroll
                for (int mt = 0; mt < 4; mt++) {
                    ah[mt] = *(const bf16x8*)&Ahi[aoff(mt, ks)];
                    al[mt] = *(const bf16x8*)&Alo[aoff(mt, ks)];
                }
                #pragma unroll
                for (int nt = 0; nt < 4; nt++) {
                    size_t bo = (size_t)(wave * 64 + nt * 16 + lm) * 256 + ks * 32 + quad * 8;
                    bf16x8 bh = *(const bf16x8*)(Wh + bo);
                    bf16x8 bl = *(const bf16x8*)(Wl + bo);
                    #pragma unroll
                    for (int mt = 0; mt < 4; mt++) {
                        acc[mt][nt] = __builtin_amdgcn_mfma_f32_16x16x32_bf16(ah[mt], bh, acc[mt][nt], 0, 0, 0);
                        acc[mt][nt] = __builtin_amdgcn_mfma_f32_16x16x32_bf16(al[mt], bh, acc[mt][nt], 0, 0, 0);
                        acc[mt][nt] = __builtin_amdgcn_mfma_f32_16x16x32_bf16(ah[mt], bl, acc[mt][nt], 0, 0, 0);
                    }
                }
            }
        }
        epi(bs[l], ld(as_[l], 0));
    }
    // ---- layer 4 + sigmoid; S_conv from LDS sc ----
    {
        int mt = wave;
        short8 z8 = {0, 0, 0, 0, 0, 0, 0, 0};
        bf16x8 bz = __builtin_bit_cast(bf16x8, z8);
        floatx4 a4 = z;
        #pragma unroll
        for (int ks = 0; ks < 8; ks++) {
            bf16x8 ah = *(const bf16x8*)&Ahi[aoff(mt, ks)];
            bf16x8 bh = bz;
            if (lm < 15)
                bh = *(const bf16x8*)(W4h + (size_t)lm * 256 + ks * 32 + quad * 8);
            a4 = __builtin_amdgcn_mfma_f32_16x16x32_bf16(ah, bh, a4, 0, 0, 0);
            if (!BF) {
                bf16x8 al = *(const bf16x8*)&Alo[aoff(mt, ks)];
                bf16x8 bl = bz;
                if (lm < 15)
                    bl = *(const bf16x8*)(W4l + (size_t)lm * 256 + ks * 32 + quad * 8);
                a4 = __builtin_amdgcn_mfma_f32_16x16x32_bf16(al, bh, a4, 0, 0, 0);
                a4 = __builtin_amdgcn_mfma_f32_16x16x32_bf16(ah, bl, a4, 0, 0, 0);
            }
        }
        if (lm < 15) {
            float bb = ld(b4, lm) + ld(encb, lm);
            #pragma unroll
            for (int j = 0; j < 4; j++) {
                int row = mt * 16 + quad * 4 + j;
                int t = t0 + row;
                if (t < T_DATA) {
                    float x = a4[j] + bb + sc[row * 16 + lm + 1];
                    x = fminf(fmaxf(x, -40.f), 40.f);
                    float sg = 1.f / (1.f + expf(-x));
                    if (BF) ((unsigned short*)out)[(size_t)t * 15 + lm] = f2bf(sg);
                    else    ((float*)out)[(size_t)t * 15 + lm] = sg;
                }
            }
        }
    }
}

__global__ void __launch_bounds__(256, 2) k_back(
    const void* Se, const void* V,
    const unsigned char* in_e, const unsigned char* in_i,
    const float* ker_e, const float* ker_i,
    const unsigned short* W1h, const unsigned short* W1l, const void* b1, const void* a1p,
    const unsigned short* W2h, const unsigned short* W2l, const void* b2, const void* a2p,
    const unsigned short* W3h, const unsigned short* W3l, const void* b3, const void* a3p,
    const unsigned short* W4h, const unsigned short* W4l, const void* b4,
    const void* encb, void* out) {
    __shared__ __align__(16) char smem[65536];   // union: conv arrays / Ahi+Alo
    __shared__ __align__(16) float sc[64 * 16];  // this block's S_conv tile
    __shared__ int sfl;
    int f = detect_bf(Se, &sfl);
    int tid = threadIdx.x;
    int t0 = blockIdx.x * 64;

    // ---------- phase A: conv tile ----------
    {
        float* se = (float*)smem;            // 263*17
        float* si = se + 263 * 17;
        float* ke = si + 263 * 17;           // 16*201
        float* ki = ke + 16 * 201;           // total 61496 B
        for (int idx = tid; idx < 263 * 4; idx += 256) {
            int r = idx >> 2, wi = idx & 3;
            int t = t0 - 199 + r;
            unsigned int ve = 0, vi = 0;
            if (t >= 0 && t < T_DATA) {
                ve = ((const unsigned int*)in_e)[t * 4 + wi];
                vi = ((const unsigned int*)in_i)[t * 4 + wi];
            }
            #pragma unroll
            for (int b = 0; b < 4; b++) {
                se[r * 17 + wi * 4 + b] = (float)((ve >> (8 * b)) & 0xFF);
                si[r * 17 + wi * 4 + b] = (float)((vi >> (8 * b)) & 0xFF);
            }
        }
        for (int idx = tid; idx < 3200; idx += 256) {
            int s = idx / 200, j = idx - s * 200;
            ke[s * 201 + j] = ker_e[idx];
            ki[s * 201 + j] = ker_i[idx];
        }
        __syncthreads();
        int s = tid & 15, g4 = (tid >> 4) * 4;
        float a0 = 0.f, a1 = 0.f, a2 = 0.f, a3 = 0.f;
        float w0 = se[(g4 + 199) * 17 + s], w1 = se[(g4 + 200) * 17 + s];
        float w2 = se[(g4 + 201) * 17 + s], w3 = se[(g4 + 202) * 17 + s];
        float x0 = si[(g4 + 199) * 17 + s], x1 = si[(g4 + 200) * 17 + s];
        float x2 = si[(g4 + 201) * 17 + s], x3 = si[(g4 + 202) * 17 + s];
        #pragma unroll 4
        for (int j = 0; j < 200; j++) {
            float kej = ke[s * 201 + j];
            float kij = ki[s * 201 + j];
            a0 += w0 * kej + x0 * kij;
            a1 += w1 * kej + x1 * kij;
            a2 += w2 * kej + x2 * kij;
            a3 += w3 * kej + x3 * kij;
            int lr = g4 + 198 - j; lr = lr < 0 ? 0 : lr;
            float nw = se[lr * 17 + s], nx = si[lr * 17 + s];
            w3 = w2; w2 = w1; w1 = w0; w0 = nw;
            x3 = x2; x2 = x1; x1 = x0; x0 = nx;
        }
        sc[(g4 + 0) * 16 + s] = a0;
        sc[(g4 + 1) * 16 + s] = a1;
        sc[(g4 + 2) * 16 + s] = a2;
        sc[(g4 + 3) * 16 + s] = a3;
        __syncthreads();   // conv reads done before MLP overwrites smem
    }

    // ---------- phase B: MLP ----------
    unsigned short* Ahi = (unsigned short*)smem;
    unsigned short* Alo = Ahi + 64 * 256;
    if (f)
        mlp_body<true>(V, W1h, W1l, b1, a1p, W2h, W2l, b2, a2p, W3h, W3l, b3, a3p,
                       W4h, W4l, b4, encb, sc, out, Ahi, Alo);
    else
        mlp_body<false>(V, W1h, W1l, b1, a1p, W2h, W2l, b2, a2p, W3h, W3l, b3, a3p,
                        W4h, W4l, b4, encb, sc, out, Ahi, Alo);
}

extern "C" void kernel_launch(void* const* d_in, const int* in_sizes, int n_in,
                              void* d_out, int out_size, void* d_ws, size_t ws_size,
                              hipStream_t stream) {
    const void* V    = d_in[0];
    const void* Se   = d_in[1];
    const void* Si   = d_in[2];
    const void* Ce   = d_in[3];
    const void* Ci   = d_in[4];
    const void* Ksyn = d_in[5];
    const void* tau  = d_in[6];
    const void* dly  = d_in[7];
    const void* encb = d_in[8];
    const void* W1   = d_in[9];
    const void* b1   = d_in[10];
    const void* a1   = d_in[11];
    const void* W2   = d_in[12];
    const void* b2   = d_in[13];
    const void* a2   = d_in[14];
    const void* W3   = d_in[15];
    const void* b3   = d_in[16];
    const void* a3   = d_in[17];
    const void* W4   = d_in[18];
    const void* b4   = d_in[19];

    char* w = (char*)d_ws;
    float* ker_e = (float*)(w + OFF_KERE);
    float* ker_i = (float*)(w + OFF_KERI);
    unsigned short* W1h = (unsigned short*)(w + OFF_W1H);
    unsigned short* W1l = (unsigned short*)(w + OFF_W1L);
    unsigned short* W2h = (unsigned short*)(w + OFF_W2H);
    unsigned short* W2l = (unsigned short*)(w + OFF_W2L);
    unsigned short* W3h = (unsigned short*)(w + OFF_W3H);
    unsigned short* W3l = (unsigned short*)(w + OFF_W3L);
    unsigned short* W4h = (unsigned short*)(w + OFF_W4H);
    unsigned short* W4l = (unsigned short*)(w + OFF_W4L);
    unsigned char* in_e = (unsigned char*)(w + OFF_INE);
    unsigned char* in_i = (unsigned char*)(w + OFF_INI);

    k_front<<<SPIKE_BLOCKS + SETUP_BLOCKS, 256, 0, stream>>>(
        Se, Si, Ce, Ci, Ksyn, tau, dly, W1, W2, W3, W4,
        ker_e, ker_i, W1h, W1l, W2h, W2l, W3h, W3l, W4h, W4l, in_e, in_i);
    k_back<<<313, 256, 0, stream>>>(
        Se, V, in_e, in_i, ker_e, ker_i,
        W1h, W1l, b1, a1, W2h, W2l, b2, a2, W3h, W3l, b3, a3,
        W4h, W4l, b4, encb, d_out);
}